// Round 2
// baseline (172.608 us; speedup 1.0000x reference)
//
#include <hip/hip_runtime.h>

// Tucker scoring: out[n] = sum_{p,q,r} U[i_n,p] V[j_n,q] W[k_n,r] G[p,q,r]
// P=Q=R=32, N=131072, num_time=5000.
//
// Round 2 strategy: (1) precompute H[k][p][q] = sum_r G[p,q,r] W[k,r]
// (20.5 MB in d_ws); (2) counting-sort sample indices by k (hist/scan/scatter);
// (3) one block per k: stage H[k] (4 KB) in LDS once, evaluate the ~26 samples
// of that bin as u^T H v with wave-per-sample butterflies.
// H global traffic: 536 MB (round 1 random gather) -> 20 MB (one row per k).

// ---------------------------------------------------------------------------
// build_H: H[k][pq] = sum_r G[pq][r] * W[k][r]
// ---------------------------------------------------------------------------
__global__ __launch_bounds__(256) void build_H(const float* __restrict__ G,
                                               const float* __restrict__ W,
                                               float* __restrict__ H,
                                               int num_time) {
    const int pq4 = threadIdx.x;            // owns pq in [4*pq4, 4*pq4+4)
    const int kbase = blockIdx.x * 8;

    float acc[8][4];
#pragma unroll
    for (int kk = 0; kk < 8; ++kk)
#pragma unroll
        for (int i = 0; i < 4; ++i) acc[kk][i] = 0.f;

#pragma unroll
    for (int r4 = 0; r4 < 8; ++r4) {
        float4 g[4];
#pragma unroll
        for (int i = 0; i < 4; ++i)
            g[i] = *(const float4*)(G + (size_t)(pq4 * 4 + i) * 32 + r4 * 4);
#pragma unroll
        for (int kk = 0; kk < 8; ++kk) {
            int k = kbase + kk;
            int kc = (k < num_time) ? k : (num_time - 1);
            float4 w = *(const float4*)(W + (size_t)kc * 32 + r4 * 4);
#pragma unroll
            for (int i = 0; i < 4; ++i)
                acc[kk][i] += g[i].x * w.x + g[i].y * w.y + g[i].z * w.z + g[i].w * w.w;
        }
    }

#pragma unroll
    for (int kk = 0; kk < 8; ++kk) {
        int k = kbase + kk;
        if (k < num_time) {
            float4 o = make_float4(acc[kk][0], acc[kk][1], acc[kk][2], acc[kk][3]);
            *(float4*)(H + (size_t)k * 1024 + pq4 * 4) = o;
        }
    }
}

// ---------------------------------------------------------------------------
// Counting sort by k: histogram -> exclusive scan -> scatter
// ---------------------------------------------------------------------------
__global__ __launch_bounds__(256) void hist_k(const int* __restrict__ K,
                                              int* __restrict__ counts, int n) {
    for (int idx = blockIdx.x * blockDim.x + threadIdx.x; idx < n;
         idx += gridDim.x * blockDim.x)
        atomicAdd(&counts[K[idx]], 1);
}

__global__ __launch_bounds__(1024) void scan_bins(const int* __restrict__ counts,
                                                  int* __restrict__ base,
                                                  int* __restrict__ cursor,
                                                  int nbins) {
    __shared__ int buf[1024];
    __shared__ int carry;
    if (threadIdx.x == 0) carry = 0;
    __syncthreads();
    for (int c0 = 0; c0 < nbins; c0 += 1024) {
        int idx = c0 + (int)threadIdx.x;
        int x = (idx < nbins) ? counts[idx] : 0;
        buf[threadIdx.x] = x;
        __syncthreads();
        int val = x;
        for (int off = 1; off < 1024; off <<= 1) {
            int t = (threadIdx.x >= (unsigned)off) ? buf[threadIdx.x - off] : 0;
            __syncthreads();
            val += t;
            buf[threadIdx.x] = val;
            __syncthreads();
        }
        int cin = carry;                 // carry from previous chunk
        int excl = val - x + cin;
        if (idx < nbins) { base[idx] = excl; cursor[idx] = excl; }
        __syncthreads();                 // everyone read carry before update
        if (threadIdx.x == 1023) carry = cin + val;   // val@1023 = chunk total
        __syncthreads();
    }
    if (threadIdx.x == 0) base[nbins] = carry;
}

__global__ __launch_bounds__(256) void scatter_k(const int* __restrict__ K,
                                                 int* __restrict__ cursor,
                                                 int* __restrict__ order, int n) {
    for (int idx = blockIdx.x * blockDim.x + threadIdx.x; idx < n;
         idx += gridDim.x * blockDim.x) {
        int pos = atomicAdd(&cursor[K[idx]], 1);
        order[pos] = idx;
    }
}

// ---------------------------------------------------------------------------
// Grouped eval: block b owns k=b. Stage H[k] (4 KB) in LDS, then each of the
// 4 waves processes bin samples round-robin. Lane = pg*8+qq; 4 float4 LDS
// reads + broadcast u, butterfly over pg, dot with v quad, butterfly over qq.
// ---------------------------------------------------------------------------
__global__ __launch_bounds__(256) void tucker_eval_grouped(
        const int* __restrict__ I, const int* __restrict__ J,
        const float* __restrict__ U, const float* __restrict__ V,
        const float* __restrict__ H, const int* __restrict__ base,
        const int* __restrict__ order, float* __restrict__ out) {
    __shared__ float Hs[1024];
    const int k = blockIdx.x;
    ((float4*)Hs)[threadIdx.x] = ((const float4*)(H + (size_t)k * 1024))[threadIdx.x];
    const int s0 = base[k];
    const int s1 = base[k + 1];
    __syncthreads();

    const int wave = threadIdx.x >> 6;
    const int lane = threadIdx.x & 63;
    const int qq = lane & 7;
    const int pg = lane >> 3;

    for (int s = s0 + wave; s < s1; s += 4) {
        const int n = order[s];
        const int i = I[n];
        const int j = J[n];
        const float* __restrict__ Urow = U + (size_t)i * 32;

        float4 acc = make_float4(0.f, 0.f, 0.f, 0.f);
#pragma unroll
        for (int it = 0; it < 4; ++it) {
            float4 h = ((const float4*)Hs)[lane + it * 64];   // = 8*p + qq
            float up = Urow[pg + it * 8];
            acc.x += up * h.x;
            acc.y += up * h.y;
            acc.z += up * h.z;
            acc.w += up * h.w;
        }
#pragma unroll
        for (int off = 8; off < 64; off <<= 1) {
            acc.x += __shfl_xor(acc.x, off, 64);
            acc.y += __shfl_xor(acc.y, off, 64);
            acc.z += __shfl_xor(acc.z, off, 64);
            acc.w += __shfl_xor(acc.w, off, 64);
        }
        float4 v4 = ((const float4*)(V + (size_t)j * 32))[qq];
        float sd = acc.x * v4.x + acc.y * v4.y + acc.z * v4.z + acc.w * v4.w;
        sd += __shfl_xor(sd, 1, 64);
        sd += __shfl_xor(sd, 2, 64);
        sd += __shfl_xor(sd, 4, 64);
        if (lane == 0) out[n] = sd;
    }
}

// ---------------------------------------------------------------------------
// Round-1 eval (fallback when ws holds H but not the sort arrays)
// ---------------------------------------------------------------------------
__global__ __launch_bounds__(256) void tucker_eval(const int* __restrict__ I,
                                                   const int* __restrict__ J,
                                                   const int* __restrict__ K,
                                                   const float* __restrict__ U,
                                                   const float* __restrict__ V,
                                                   const float* __restrict__ H,
                                                   float* __restrict__ out,
                                                   int n_samples) {
    const int wave = (int)((blockIdx.x * (unsigned)blockDim.x + threadIdx.x) >> 6);
    const int lane = threadIdx.x & 63;
    if (wave >= n_samples) return;

    const int i = I[wave];
    const int j = J[wave];
    const int k = K[wave];
    const int qq = lane & 7;
    const int pg = lane >> 3;

    const float4* __restrict__ Hrow = (const float4*)(H + (size_t)k * 1024);
    const float* __restrict__ Urow = U + (size_t)i * 32;

    float4 acc = make_float4(0.f, 0.f, 0.f, 0.f);
#pragma unroll
    for (int it = 0; it < 4; ++it) {
        float4 h = Hrow[lane + it * 64];
        float up = Urow[pg + it * 8];
        acc.x += up * h.x;
        acc.y += up * h.y;
        acc.z += up * h.z;
        acc.w += up * h.w;
    }
#pragma unroll
    for (int off = 8; off < 64; off <<= 1) {
        acc.x += __shfl_xor(acc.x, off, 64);
        acc.y += __shfl_xor(acc.y, off, 64);
        acc.z += __shfl_xor(acc.z, off, 64);
        acc.w += __shfl_xor(acc.w, off, 64);
    }
    float4 v4 = ((const float4*)(V + (size_t)j * 32))[qq];
    float s = acc.x * v4.x + acc.y * v4.y + acc.z * v4.z + acc.w * v4.w;
    s += __shfl_xor(s, 1, 64);
    s += __shfl_xor(s, 2, 64);
    s += __shfl_xor(s, 4, 64);
    if (lane == 0) out[wave] = s;
}

// ---------------------------------------------------------------------------
// Last-resort direct path (tiny ws): G streamed through LDS.
// ---------------------------------------------------------------------------
__global__ __launch_bounds__(256) void tucker_direct(const int* __restrict__ I,
                                                     const int* __restrict__ J,
                                                     const int* __restrict__ K,
                                                     const float* __restrict__ U,
                                                     const float* __restrict__ V,
                                                     const float* __restrict__ W,
                                                     const float* __restrict__ G,
                                                     float* __restrict__ out,
                                                     int n_samples) {
    __shared__ float Gc[4 * 32 * 32];
    const int n = blockIdx.x * blockDim.x + threadIdx.x;
    const bool active = (n < n_samples);

    int i = 0, j = 0, k = 0;
    if (active) { i = I[n]; j = J[n]; k = K[n]; }

    float4 w4[8];
#pragma unroll
    for (int r4 = 0; r4 < 8; ++r4)
        w4[r4] = ((const float4*)(W + (size_t)k * 32))[r4];

    float v[32];
#pragma unroll
    for (int q4 = 0; q4 < 8; ++q4) {
        float4 t = ((const float4*)(V + (size_t)j * 32))[q4];
        v[q4 * 4 + 0] = t.x; v[q4 * 4 + 1] = t.y;
        v[q4 * 4 + 2] = t.z; v[q4 * 4 + 3] = t.w;
    }

    const float* __restrict__ Urow = U + (size_t)i * 32;
    float acc = 0.f;

    for (int c = 0; c < 8; ++c) {
        __syncthreads();
#pragma unroll
        for (int t = 0; t < 4; ++t) {
            int idx = threadIdx.x + t * 256;
            ((float4*)Gc)[idx] = ((const float4*)(G + (size_t)c * 4096))[idx];
        }
        __syncthreads();
        for (int pp = 0; pp < 4; ++pp) {
            float up = Urow[c * 4 + pp];
#pragma unroll
            for (int q = 0; q < 32; ++q) {
                float t0 = 0.f;
#pragma unroll
                for (int r4 = 0; r4 < 8; ++r4) {
                    float4 g = ((const float4*)Gc)[pp * 256 + q * 8 + r4];
                    t0 += g.x * w4[r4].x + g.y * w4[r4].y + g.z * w4[r4].z + g.w * w4[r4].w;
                }
                acc += up * v[q] * t0;
            }
        }
    }
    if (active) out[n] = acc;
}

extern "C" void kernel_launch(void* const* d_in, const int* in_sizes, int n_in,
                              void* d_out, int out_size, void* d_ws, size_t ws_size,
                              hipStream_t stream) {
    const int*   I = (const int*)d_in[0];
    const int*   J = (const int*)d_in[1];
    const int*   K = (const int*)d_in[2];
    const float* U = (const float*)d_in[3];   // [NUM_USER, 32]
    const float* V = (const float*)d_in[4];   // [NUM_ITEM, 32]
    const float* W = (const float*)d_in[5];   // [NUM_TIME, 32]
    const float* G = (const float*)d_in[6];   // [32, 32, 32]
    float* out = (float*)d_out;

    const int n_samples = in_sizes[0];
    const int num_time = in_sizes[5] / 32;

    const size_t h_bytes = (size_t)num_time * 1024 * sizeof(float);
    const size_t sort_bytes = ((size_t)(3 * num_time + 1) + (size_t)n_samples) * sizeof(int);
    const size_t need_full = h_bytes + sort_bytes;

    if (ws_size >= need_full) {
        float* H      = (float*)d_ws;
        int*   basep  = (int*)((char*)d_ws + h_bytes);   // num_time+1
        int*   cursor = basep + num_time + 1;            // num_time
        int*   counts = cursor + num_time;               // num_time
        int*   order  = counts + num_time;               // n_samples

        hipMemsetAsync(counts, 0, (size_t)num_time * sizeof(int), stream);
        hist_k<<<512, 256, 0, stream>>>(K, counts, n_samples);
        scan_bins<<<1, 1024, 0, stream>>>(counts, basep, cursor, num_time);
        scatter_k<<<512, 256, 0, stream>>>(K, cursor, order, n_samples);

        build_H<<<(num_time + 7) / 8, 256, 0, stream>>>(G, W, H, num_time);

        tucker_eval_grouped<<<num_time, 256, 0, stream>>>(I, J, U, V, H, basep,
                                                          order, out);
    } else if (ws_size >= h_bytes) {
        float* H = (float*)d_ws;
        build_H<<<(num_time + 7) / 8, 256, 0, stream>>>(G, W, H, num_time);
        const long long total_threads = (long long)n_samples * 64;
        tucker_eval<<<(int)((total_threads + 255) / 256), 256, 0, stream>>>(
            I, J, K, U, V, H, out, n_samples);
    } else {
        tucker_direct<<<(n_samples + 255) / 256, 256, 0, stream>>>(
            I, J, K, U, V, W, G, out, n_samples);
    }
}

// Round 3
// 154.604 us; speedup vs baseline: 1.1164x; 1.1164x over previous
//
#include <hip/hip_runtime.h>

// Tucker scoring: out[n] = sum_{p,q,r} U[i_n,p] V[j_n,q] W[k_n,r] G[p,q,r]
// P=Q=R=32, N=131072, num_time=5000.
//
// Round 3: (1) build_H precomputes H[k][p][q] = sum_r G[p,q,r] W[k,r];
// (2) scatter bins samples by k into fixed-capacity bins with PACKED records
//     {n,i,j,k} (no histogram, no scan); (3) eval: one block (2 waves) per k,
//     the 4KB H[k] row lives in 16 VGPRs per wave (no LDS, no barrier),
//     lane-parallel record preload + depth-1 software pipeline on U/V gathers.
// Overflow beyond CAP=128/bin (statistically never at lambda~26) spills to a
// list handled by a separate wave-per-sample kernel for correctness.

#define BIN_CAP 128

// ---------------------------------------------------------------------------
// build_H: H[k][pq] = sum_r G[pq][r] * W[k][r]
// ---------------------------------------------------------------------------
__global__ __launch_bounds__(256) void build_H(const float* __restrict__ G,
                                               const float* __restrict__ W,
                                               float* __restrict__ H,
                                               int num_time) {
    const int pq4 = threadIdx.x;            // owns pq in [4*pq4, 4*pq4+4)
    const int kbase = blockIdx.x * 8;

    float acc[8][4];
#pragma unroll
    for (int kk = 0; kk < 8; ++kk)
#pragma unroll
        for (int i = 0; i < 4; ++i) acc[kk][i] = 0.f;

#pragma unroll
    for (int r4 = 0; r4 < 8; ++r4) {
        float4 g[4];
#pragma unroll
        for (int i = 0; i < 4; ++i)
            g[i] = *(const float4*)(G + (size_t)(pq4 * 4 + i) * 32 + r4 * 4);
#pragma unroll
        for (int kk = 0; kk < 8; ++kk) {
            int k = kbase + kk;
            int kc = (k < num_time) ? k : (num_time - 1);
            float4 w = *(const float4*)(W + (size_t)kc * 32 + r4 * 4);
#pragma unroll
            for (int i = 0; i < 4; ++i)
                acc[kk][i] += g[i].x * w.x + g[i].y * w.y + g[i].z * w.z + g[i].w * w.w;
        }
    }

#pragma unroll
    for (int kk = 0; kk < 8; ++kk) {
        int k = kbase + kk;
        if (k < num_time) {
            float4 o = make_float4(acc[kk][0], acc[kk][1], acc[kk][2], acc[kk][3]);
            *(float4*)(H + (size_t)k * 1024 + pq4 * 4) = o;
        }
    }
}

// ---------------------------------------------------------------------------
// scatter: bin samples by k with packed records {n, i, j, k}.
// ---------------------------------------------------------------------------
__global__ __launch_bounds__(256) void scatter_k(const int* __restrict__ K,
                                                 const int* __restrict__ I,
                                                 const int* __restrict__ J,
                                                 int* __restrict__ counts,
                                                 int4* __restrict__ bins,
                                                 int* __restrict__ ovf_cnt,
                                                 int4* __restrict__ ovf,
                                                 int n) {
    for (int idx = blockIdx.x * blockDim.x + threadIdx.x; idx < n;
         idx += gridDim.x * blockDim.x) {
        int k = K[idx];
        int4 rec = make_int4(idx, I[idx], J[idx], k);
        int pos = atomicAdd(&counts[k], 1);
        if (pos < BIN_CAP) {
            bins[(size_t)k * BIN_CAP + pos] = rec;
        } else {
            int o = atomicAdd(ovf_cnt, 1);
            ovf[o] = rec;
        }
    }
}

// ---------------------------------------------------------------------------
// eval: block b owns k=b, 128 threads = 2 waves; wave w takes the first/second
// half of the bin. The wave's H[k] fragment (16 floats/lane = whole 4KB row)
// is loaded once into registers. Lane = pg*8+qq. Per sample: 16 reg-fma,
// butterfly over pg (xor 8/16/32), dot with v quad, butterfly over qq
// (xor 1/2/4), lane 0 stores. Depth-1 pipeline on (n,i,j)+U/V.
// ---------------------------------------------------------------------------
__global__ __launch_bounds__(128) void tucker_eval_grouped(
        const float* __restrict__ U, const float* __restrict__ V,
        const float* __restrict__ H, const int* __restrict__ counts,
        const int4* __restrict__ bins, float* __restrict__ out) {
    const int k = blockIdx.x;
    const int wave = threadIdx.x >> 6;
    const int lane = threadIdx.x & 63;
    const int qq = lane & 7;
    const int pg = lane >> 3;

    // whole H[k] row distributed across the wave's registers
    const float4* __restrict__ Hrow = (const float4*)(H + (size_t)k * 1024);
    float4 h0 = Hrow[lane];
    float4 h1 = Hrow[lane + 64];
    float4 h2 = Hrow[lane + 128];
    float4 h3 = Hrow[lane + 192];

    int cnt = counts[k];
    cnt = (cnt < BIN_CAP) ? cnt : BIN_CAP;
    const int half = (cnt + 1) >> 1;
    const int b0 = wave ? half : 0;
    const int e0 = wave ? cnt : half;
    const int m = e0 - b0;                       // <= 64
    if (m <= 0) return;

    // lane-parallel record preload: one coalesced int4 per lane
    int4 rec = bins[(size_t)k * BIN_CAP + b0 + lane];

    // prefetch sample 0
    int nc = __shfl(rec.x, 0, 64);
    int ic = __shfl(rec.y, 0, 64);
    int jc = __shfl(rec.z, 0, 64);
    const float* Ur = U + (size_t)ic * 32;
    float uc0 = Ur[pg], uc1 = Ur[pg + 8], uc2 = Ur[pg + 16], uc3 = Ur[pg + 24];
    float4 vc = ((const float4*)(V + (size_t)jc * 32))[qq];

    for (int t = 0; t < m; ++t) {
        // issue next sample's loads before consuming current
        const int tsel = (t + 1 < m) ? (t + 1) : t;
        const int nn = __shfl(rec.x, tsel, 64);
        const int in_ = __shfl(rec.y, tsel, 64);
        const int jn = __shfl(rec.z, tsel, 64);
        const float* Ur2 = U + (size_t)in_ * 32;
        float un0 = Ur2[pg], un1 = Ur2[pg + 8], un2 = Ur2[pg + 16], un3 = Ur2[pg + 24];
        float4 vn = ((const float4*)(V + (size_t)jn * 32))[qq];

        // compute current: acc_qq = sum_p u_p * H[p][qq-quad]
        float4 acc;
        acc.x = uc0 * h0.x; acc.y = uc0 * h0.y; acc.z = uc0 * h0.z; acc.w = uc0 * h0.w;
        acc.x += uc1 * h1.x; acc.y += uc1 * h1.y; acc.z += uc1 * h1.z; acc.w += uc1 * h1.w;
        acc.x += uc2 * h2.x; acc.y += uc2 * h2.y; acc.z += uc2 * h2.z; acc.w += uc2 * h2.w;
        acc.x += uc3 * h3.x; acc.y += uc3 * h3.y; acc.z += uc3 * h3.z; acc.w += uc3 * h3.w;

#pragma unroll
        for (int off = 8; off < 64; off <<= 1) {
            acc.x += __shfl_xor(acc.x, off, 64);
            acc.y += __shfl_xor(acc.y, off, 64);
            acc.z += __shfl_xor(acc.z, off, 64);
            acc.w += __shfl_xor(acc.w, off, 64);
        }
        float sd = acc.x * vc.x + acc.y * vc.y + acc.z * vc.z + acc.w * vc.w;
        sd += __shfl_xor(sd, 1, 64);
        sd += __shfl_xor(sd, 2, 64);
        sd += __shfl_xor(sd, 4, 64);
        if (lane == 0) out[nc] = sd;

        nc = nn; uc0 = un0; uc1 = un1; uc2 = un2; uc3 = un3; vc = vn;
    }
}

// ---------------------------------------------------------------------------
// overflow spill: wave per sample, H row from global (rare/never path)
// ---------------------------------------------------------------------------
__global__ __launch_bounds__(256) void tucker_eval_overflow(
        const float* __restrict__ U, const float* __restrict__ V,
        const float* __restrict__ H, const int* __restrict__ ovf_cnt,
        const int4* __restrict__ ovf, float* __restrict__ out) {
    const int gwave = (int)((blockIdx.x * (unsigned)blockDim.x + threadIdx.x) >> 6);
    const int nwaves = (int)((gridDim.x * (unsigned)blockDim.x) >> 6);
    const int lane = threadIdx.x & 63;
    const int qq = lane & 7;
    const int pg = lane >> 3;
    const int cnt = *ovf_cnt;

    for (int s = gwave; s < cnt; s += nwaves) {
        int4 rec = ovf[s];
        const float4* __restrict__ Hrow = (const float4*)(H + (size_t)rec.w * 1024);
        const float* __restrict__ Ur = U + (size_t)rec.y * 32;

        float4 acc = make_float4(0.f, 0.f, 0.f, 0.f);
#pragma unroll
        for (int it = 0; it < 4; ++it) {
            float4 h = Hrow[lane + it * 64];
            float up = Ur[pg + it * 8];
            acc.x += up * h.x; acc.y += up * h.y;
            acc.z += up * h.z; acc.w += up * h.w;
        }
#pragma unroll
        for (int off = 8; off < 64; off <<= 1) {
            acc.x += __shfl_xor(acc.x, off, 64);
            acc.y += __shfl_xor(acc.y, off, 64);
            acc.z += __shfl_xor(acc.z, off, 64);
            acc.w += __shfl_xor(acc.w, off, 64);
        }
        float4 v4 = ((const float4*)(V + (size_t)rec.z * 32))[qq];
        float sd = acc.x * v4.x + acc.y * v4.y + acc.z * v4.z + acc.w * v4.w;
        sd += __shfl_xor(sd, 1, 64);
        sd += __shfl_xor(sd, 2, 64);
        sd += __shfl_xor(sd, 4, 64);
        if (lane == 0) out[rec.x] = sd;
    }
}

// ---------------------------------------------------------------------------
// Fallbacks for small workspace (round-1 paths)
// ---------------------------------------------------------------------------
__global__ __launch_bounds__(256) void tucker_eval(const int* __restrict__ I,
                                                   const int* __restrict__ J,
                                                   const int* __restrict__ K,
                                                   const float* __restrict__ U,
                                                   const float* __restrict__ V,
                                                   const float* __restrict__ H,
                                                   float* __restrict__ out,
                                                   int n_samples) {
    const int wave = (int)((blockIdx.x * (unsigned)blockDim.x + threadIdx.x) >> 6);
    const int lane = threadIdx.x & 63;
    if (wave >= n_samples) return;
    const int i = I[wave];
    const int j = J[wave];
    const int k = K[wave];
    const int qq = lane & 7;
    const int pg = lane >> 3;
    const float4* __restrict__ Hrow = (const float4*)(H + (size_t)k * 1024);
    const float* __restrict__ Urow = U + (size_t)i * 32;
    float4 acc = make_float4(0.f, 0.f, 0.f, 0.f);
#pragma unroll
    for (int it = 0; it < 4; ++it) {
        float4 h = Hrow[lane + it * 64];
        float up = Urow[pg + it * 8];
        acc.x += up * h.x; acc.y += up * h.y;
        acc.z += up * h.z; acc.w += up * h.w;
    }
#pragma unroll
    for (int off = 8; off < 64; off <<= 1) {
        acc.x += __shfl_xor(acc.x, off, 64);
        acc.y += __shfl_xor(acc.y, off, 64);
        acc.z += __shfl_xor(acc.z, off, 64);
        acc.w += __shfl_xor(acc.w, off, 64);
    }
    float4 v4 = ((const float4*)(V + (size_t)j * 32))[qq];
    float s = acc.x * v4.x + acc.y * v4.y + acc.z * v4.z + acc.w * v4.w;
    s += __shfl_xor(s, 1, 64);
    s += __shfl_xor(s, 2, 64);
    s += __shfl_xor(s, 4, 64);
    if (lane == 0) out[wave] = s;
}

__global__ __launch_bounds__(256) void tucker_direct(const int* __restrict__ I,
                                                     const int* __restrict__ J,
                                                     const int* __restrict__ K,
                                                     const float* __restrict__ U,
                                                     const float* __restrict__ V,
                                                     const float* __restrict__ W,
                                                     const float* __restrict__ G,
                                                     float* __restrict__ out,
                                                     int n_samples) {
    __shared__ float Gc[4 * 32 * 32];
    const int n = blockIdx.x * blockDim.x + threadIdx.x;
    const bool active = (n < n_samples);
    int i = 0, j = 0, k = 0;
    if (active) { i = I[n]; j = J[n]; k = K[n]; }
    float4 w4[8];
#pragma unroll
    for (int r4 = 0; r4 < 8; ++r4)
        w4[r4] = ((const float4*)(W + (size_t)k * 32))[r4];
    float v[32];
#pragma unroll
    for (int q4 = 0; q4 < 8; ++q4) {
        float4 t = ((const float4*)(V + (size_t)j * 32))[q4];
        v[q4 * 4 + 0] = t.x; v[q4 * 4 + 1] = t.y;
        v[q4 * 4 + 2] = t.z; v[q4 * 4 + 3] = t.w;
    }
    const float* __restrict__ Urow = U + (size_t)i * 32;
    float acc = 0.f;
    for (int c = 0; c < 8; ++c) {
        __syncthreads();
#pragma unroll
        for (int t = 0; t < 4; ++t) {
            int idx = threadIdx.x + t * 256;
            ((float4*)Gc)[idx] = ((const float4*)(G + (size_t)c * 4096))[idx];
        }
        __syncthreads();
        for (int pp = 0; pp < 4; ++pp) {
            float up = Urow[c * 4 + pp];
#pragma unroll
            for (int q = 0; q < 32; ++q) {
                float t0 = 0.f;
#pragma unroll
                for (int r4 = 0; r4 < 8; ++r4) {
                    float4 g = ((const float4*)Gc)[pp * 256 + q * 8 + r4];
                    t0 += g.x * w4[r4].x + g.y * w4[r4].y + g.z * w4[r4].z + g.w * w4[r4].w;
                }
                acc += up * v[q] * t0;
            }
        }
    }
    if (active) out[n] = acc;
}

extern "C" void kernel_launch(void* const* d_in, const int* in_sizes, int n_in,
                              void* d_out, int out_size, void* d_ws, size_t ws_size,
                              hipStream_t stream) {
    const int*   I = (const int*)d_in[0];
    const int*   J = (const int*)d_in[1];
    const int*   K = (const int*)d_in[2];
    const float* U = (const float*)d_in[3];   // [NUM_USER, 32]
    const float* V = (const float*)d_in[4];   // [NUM_ITEM, 32]
    const float* W = (const float*)d_in[5];   // [NUM_TIME, 32]
    const float* G = (const float*)d_in[6];   // [32, 32, 32]
    float* out = (float*)d_out;

    const int n_samples = in_sizes[0];
    const int num_time = in_sizes[5] / 32;

    const size_t h_bytes = (size_t)num_time * 1024 * sizeof(float);
    const size_t z_bytes = (size_t)(num_time + 1) * sizeof(int);   // counts + ovf_cnt
    const size_t z_pad = (z_bytes + 15) & ~(size_t)15;
    const size_t bins_bytes = (size_t)num_time * BIN_CAP * sizeof(int4);
    const size_t ovf_bytes = (size_t)n_samples * sizeof(int4);
    const size_t need_full = h_bytes + z_pad + bins_bytes + ovf_bytes;

    if (ws_size >= need_full) {
        float* H       = (float*)d_ws;
        int*   counts  = (int*)((char*)d_ws + h_bytes);      // num_time
        int*   ovf_cnt = counts + num_time;                  // 1
        int4*  bins    = (int4*)((char*)d_ws + h_bytes + z_pad);
        int4*  ovf     = (int4*)((char*)d_ws + h_bytes + z_pad + bins_bytes);

        hipMemsetAsync(counts, 0, z_bytes, stream);
        scatter_k<<<512, 256, 0, stream>>>(K, I, J, counts, bins, ovf_cnt, ovf,
                                           n_samples);
        build_H<<<(num_time + 7) / 8, 256, 0, stream>>>(G, W, H, num_time);
        tucker_eval_grouped<<<num_time, 128, 0, stream>>>(U, V, H, counts, bins,
                                                          out);
        tucker_eval_overflow<<<64, 256, 0, stream>>>(U, V, H, ovf_cnt, ovf, out);
    } else if (ws_size >= h_bytes) {
        float* H = (float*)d_ws;
        build_H<<<(num_time + 7) / 8, 256, 0, stream>>>(G, W, H, num_time);
        const long long total_threads = (long long)n_samples * 64;
        tucker_eval<<<(int)((total_threads + 255) / 256), 256, 0, stream>>>(
            I, J, K, U, V, H, out, n_samples);
    } else {
        tucker_direct<<<(n_samples + 255) / 256, 256, 0, stream>>>(
            I, J, K, U, V, W, G, out, n_samples);
    }
}

// Round 4
// 136.643 us; speedup vs baseline: 1.2632x; 1.1314x over previous
//
#include <hip/hip_runtime.h>

// Tucker scoring: out[n] = sum_{p,q,r} U[i_n,p] V[j_n,q] W[k_n,r] G[p,q,r]
// P=Q=R=32, N=131072, num_time=5000.
//
// Round 4: (1) build_H: H[k][p][q] = sum_r G[p,q,r] W[k,r]; (2) scatter_k:
// bin samples by k with packed {n,i,j,k} records (fixed CAP=128, overflow
// spill list); (3) eval: wave per k (4 k's per 256-thread block), H[k] in
// 4KB LDS, lane-group-per-sample: 8 lanes x 8 concurrent samples per wave
// iteration. Each lane loads its sample's U row (8 float4) + V quad + record
// independently (massive MLP, no serial chain), H via conflict-free
// ds_read_b128 broadcasts, reduction is 3 shfl_xor over the 8-lane group.

#define BIN_CAP 128

// ---------------------------------------------------------------------------
// build_H: H[k][pq] = sum_r G[pq][r] * W[k][r]
// ---------------------------------------------------------------------------
__global__ __launch_bounds__(256) void build_H(const float* __restrict__ G,
                                               const float* __restrict__ W,
                                               float* __restrict__ H,
                                               int num_time) {
    const int pq4 = threadIdx.x;            // owns pq in [4*pq4, 4*pq4+4)
    const int kbase = blockIdx.x * 8;

    float acc[8][4];
#pragma unroll
    for (int kk = 0; kk < 8; ++kk)
#pragma unroll
        for (int i = 0; i < 4; ++i) acc[kk][i] = 0.f;

#pragma unroll
    for (int r4 = 0; r4 < 8; ++r4) {
        float4 g[4];
#pragma unroll
        for (int i = 0; i < 4; ++i)
            g[i] = *(const float4*)(G + (size_t)(pq4 * 4 + i) * 32 + r4 * 4);
#pragma unroll
        for (int kk = 0; kk < 8; ++kk) {
            int k = kbase + kk;
            int kc = (k < num_time) ? k : (num_time - 1);
            float4 w = *(const float4*)(W + (size_t)kc * 32 + r4 * 4);
#pragma unroll
            for (int i = 0; i < 4; ++i)
                acc[kk][i] += g[i].x * w.x + g[i].y * w.y + g[i].z * w.z + g[i].w * w.w;
        }
    }

#pragma unroll
    for (int kk = 0; kk < 8; ++kk) {
        int k = kbase + kk;
        if (k < num_time) {
            float4 o = make_float4(acc[kk][0], acc[kk][1], acc[kk][2], acc[kk][3]);
            *(float4*)(H + (size_t)k * 1024 + pq4 * 4) = o;
        }
    }
}

// ---------------------------------------------------------------------------
// scatter: bin samples by k with packed records {n, i, j, k}.
// ---------------------------------------------------------------------------
__global__ __launch_bounds__(256) void scatter_k(const int* __restrict__ K,
                                                 const int* __restrict__ I,
                                                 const int* __restrict__ J,
                                                 int* __restrict__ counts,
                                                 int4* __restrict__ bins,
                                                 int* __restrict__ ovf_cnt,
                                                 int4* __restrict__ ovf,
                                                 int n) {
    for (int idx = blockIdx.x * blockDim.x + threadIdx.x; idx < n;
         idx += gridDim.x * blockDim.x) {
        int k = K[idx];
        int4 rec = make_int4(idx, I[idx], J[idx], k);
        int pos = atomicAdd(&counts[k], 1);
        if (pos < BIN_CAP) {
            bins[(size_t)k * BIN_CAP + pos] = rec;
        } else {
            int o = atomicAdd(ovf_cnt, 1);
            ovf[o] = rec;
        }
    }
}

// ---------------------------------------------------------------------------
// eval: 256-thread block = 4 waves; wave w owns k = 4*blockIdx + w.
// H[k] (4KB) staged to LDS per wave. Lane = s8*8 + qq: sample slot s8,
// q-quad qq. 8 samples concurrently per wave iteration; per lane:
//   acc4[qq] = sum_p u_p * H[p][4qq..4qq+3]   (32 ds_read_b128 broadcasts)
//   partial  = dot(acc4, v4[qq]); reduce over qq via shfl_xor 1/2/4.
// All global loads (record, 8x U float4, V float4) are per-lane independent.
// ---------------------------------------------------------------------------
__global__ __launch_bounds__(256) void tucker_eval_grouped(
        const float* __restrict__ U, const float* __restrict__ V,
        const float* __restrict__ H, const int* __restrict__ counts,
        const int4* __restrict__ bins, float* __restrict__ out,
        int num_time) {
    __shared__ float4 Hs4[4][256];           // 16 KB: one H row per wave
    const int wave = threadIdx.x >> 6;
    const int lane = threadIdx.x & 63;
    const int k = blockIdx.x * 4 + wave;
    const int qq = lane & 7;                 // q-quad
    const int s8 = lane >> 3;                // sample slot within iteration

    int m = 0;
    if (k < num_time) {
        // stage H[k] -> LDS (coalesced float4, identical layout)
        const float4* __restrict__ Hrow4 = (const float4*)(H + (size_t)k * 1024);
#pragma unroll
        for (int c = 0; c < 4; ++c)
            Hs4[wave][lane + 64 * c] = Hrow4[lane + 64 * c];
        m = counts[k];
        m = (m < BIN_CAP) ? m : BIN_CAP;
    }
    __syncthreads();
    if (k >= num_time || m == 0) return;

    const int iters = (m + 7) >> 3;
    const float4* __restrict__ Hw = Hs4[wave];

    for (int t = 0; t < iters; ++t) {
        const int s = t * 8 + s8;
        if (s < m) {                          // whole 8-lane group uniform
            int4 rec = bins[(size_t)k * BIN_CAP + s];
            const float4* __restrict__ Ur = (const float4*)(U + (size_t)rec.y * 32);
            float4 u[8];
#pragma unroll
            for (int p4 = 0; p4 < 8; ++p4) u[p4] = Ur[p4];
            float4 v4 = ((const float4*)(V + (size_t)rec.z * 32))[qq];

            float4 acc = make_float4(0.f, 0.f, 0.f, 0.f);
#pragma unroll
            for (int p4 = 0; p4 < 8; ++p4) {
                float4 h;
                h = Hw[(p4 * 4 + 0) * 8 + qq];
                acc.x += u[p4].x * h.x; acc.y += u[p4].x * h.y;
                acc.z += u[p4].x * h.z; acc.w += u[p4].x * h.w;
                h = Hw[(p4 * 4 + 1) * 8 + qq];
                acc.x += u[p4].y * h.x; acc.y += u[p4].y * h.y;
                acc.z += u[p4].y * h.z; acc.w += u[p4].y * h.w;
                h = Hw[(p4 * 4 + 2) * 8 + qq];
                acc.x += u[p4].z * h.x; acc.y += u[p4].z * h.y;
                acc.z += u[p4].z * h.z; acc.w += u[p4].z * h.w;
                h = Hw[(p4 * 4 + 3) * 8 + qq];
                acc.x += u[p4].w * h.x; acc.y += u[p4].w * h.y;
                acc.z += u[p4].w * h.z; acc.w += u[p4].w * h.w;
            }
            float sd = acc.x * v4.x + acc.y * v4.y + acc.z * v4.z + acc.w * v4.w;
            sd += __shfl_xor(sd, 1, 64);
            sd += __shfl_xor(sd, 2, 64);
            sd += __shfl_xor(sd, 4, 64);
            if (qq == 0) out[rec.x] = sd;
        }
    }
}

// ---------------------------------------------------------------------------
// overflow spill: wave per sample, H row from global (rare/never path)
// ---------------------------------------------------------------------------
__global__ __launch_bounds__(256) void tucker_eval_overflow(
        const float* __restrict__ U, const float* __restrict__ V,
        const float* __restrict__ H, const int* __restrict__ ovf_cnt,
        const int4* __restrict__ ovf, float* __restrict__ out) {
    const int gwave = (int)((blockIdx.x * (unsigned)blockDim.x + threadIdx.x) >> 6);
    const int nwaves = (int)((gridDim.x * (unsigned)blockDim.x) >> 6);
    const int lane = threadIdx.x & 63;
    const int qq = lane & 7;
    const int pg = lane >> 3;
    const int cnt = *ovf_cnt;

    for (int s = gwave; s < cnt; s += nwaves) {
        int4 rec = ovf[s];
        const float4* __restrict__ Hrow = (const float4*)(H + (size_t)rec.w * 1024);
        const float* __restrict__ Ur = U + (size_t)rec.y * 32;

        float4 acc = make_float4(0.f, 0.f, 0.f, 0.f);
#pragma unroll
        for (int it = 0; it < 4; ++it) {
            float4 h = Hrow[lane + it * 64];
            float up = Ur[pg + it * 8];
            acc.x += up * h.x; acc.y += up * h.y;
            acc.z += up * h.z; acc.w += up * h.w;
        }
#pragma unroll
        for (int off = 8; off < 64; off <<= 1) {
            acc.x += __shfl_xor(acc.x, off, 64);
            acc.y += __shfl_xor(acc.y, off, 64);
            acc.z += __shfl_xor(acc.z, off, 64);
            acc.w += __shfl_xor(acc.w, off, 64);
        }
        float4 v4 = ((const float4*)(V + (size_t)rec.z * 32))[qq];
        float sd = acc.x * v4.x + acc.y * v4.y + acc.z * v4.z + acc.w * v4.w;
        sd += __shfl_xor(sd, 1, 64);
        sd += __shfl_xor(sd, 2, 64);
        sd += __shfl_xor(sd, 4, 64);
        if (lane == 0) out[rec.x] = sd;
    }
}

// ---------------------------------------------------------------------------
// Fallbacks for small workspace
// ---------------------------------------------------------------------------
__global__ __launch_bounds__(256) void tucker_eval(const int* __restrict__ I,
                                                   const int* __restrict__ J,
                                                   const int* __restrict__ K,
                                                   const float* __restrict__ U,
                                                   const float* __restrict__ V,
                                                   const float* __restrict__ H,
                                                   float* __restrict__ out,
                                                   int n_samples) {
    const int wave = (int)((blockIdx.x * (unsigned)blockDim.x + threadIdx.x) >> 6);
    const int lane = threadIdx.x & 63;
    if (wave >= n_samples) return;
    const int i = I[wave];
    const int j = J[wave];
    const int k = K[wave];
    const int qq = lane & 7;
    const int pg = lane >> 3;
    const float4* __restrict__ Hrow = (const float4*)(H + (size_t)k * 1024);
    const float* __restrict__ Urow = U + (size_t)i * 32;
    float4 acc = make_float4(0.f, 0.f, 0.f, 0.f);
#pragma unroll
    for (int it = 0; it < 4; ++it) {
        float4 h = Hrow[lane + it * 64];
        float up = Urow[pg + it * 8];
        acc.x += up * h.x; acc.y += up * h.y;
        acc.z += up * h.z; acc.w += up * h.w;
    }
#pragma unroll
    for (int off = 8; off < 64; off <<= 1) {
        acc.x += __shfl_xor(acc.x, off, 64);
        acc.y += __shfl_xor(acc.y, off, 64);
        acc.z += __shfl_xor(acc.z, off, 64);
        acc.w += __shfl_xor(acc.w, off, 64);
    }
    float4 v4 = ((const float4*)(V + (size_t)j * 32))[qq];
    float s = acc.x * v4.x + acc.y * v4.y + acc.z * v4.z + acc.w * v4.w;
    s += __shfl_xor(s, 1, 64);
    s += __shfl_xor(s, 2, 64);
    s += __shfl_xor(s, 4, 64);
    if (lane == 0) out[wave] = s;
}

__global__ __launch_bounds__(256) void tucker_direct(const int* __restrict__ I,
                                                     const int* __restrict__ J,
                                                     const int* __restrict__ K,
                                                     const float* __restrict__ U,
                                                     const float* __restrict__ V,
                                                     const float* __restrict__ W,
                                                     const float* __restrict__ G,
                                                     float* __restrict__ out,
                                                     int n_samples) {
    __shared__ float Gc[4 * 32 * 32];
    const int n = blockIdx.x * blockDim.x + threadIdx.x;
    const bool active = (n < n_samples);
    int i = 0, j = 0, k = 0;
    if (active) { i = I[n]; j = J[n]; k = K[n]; }
    float4 w4[8];
#pragma unroll
    for (int r4 = 0; r4 < 8; ++r4)
        w4[r4] = ((const float4*)(W + (size_t)k * 32))[r4];
    float v[32];
#pragma unroll
    for (int q4 = 0; q4 < 8; ++q4) {
        float4 t = ((const float4*)(V + (size_t)j * 32))[q4];
        v[q4 * 4 + 0] = t.x; v[q4 * 4 + 1] = t.y;
        v[q4 * 4 + 2] = t.z; v[q4 * 4 + 3] = t.w;
    }
    const float* __restrict__ Urow = U + (size_t)i * 32;
    float acc = 0.f;
    for (int c = 0; c < 8; ++c) {
        __syncthreads();
#pragma unroll
        for (int t = 0; t < 4; ++t) {
            int idx = threadIdx.x + t * 256;
            ((float4*)Gc)[idx] = ((const float4*)(G + (size_t)c * 4096))[idx];
        }
        __syncthreads();
        for (int pp = 0; pp < 4; ++pp) {
            float up = Urow[c * 4 + pp];
#pragma unroll
            for (int q = 0; q < 32; ++q) {
                float t0 = 0.f;
#pragma unroll
                for (int r4 = 0; r4 < 8; ++r4) {
                    float4 g = ((const float4*)Gc)[pp * 256 + q * 8 + r4];
                    t0 += g.x * w4[r4].x + g.y * w4[r4].y + g.z * w4[r4].z + g.w * w4[r4].w;
                }
                acc += up * v[q] * t0;
            }
        }
    }
    if (active) out[n] = acc;
}

extern "C" void kernel_launch(void* const* d_in, const int* in_sizes, int n_in,
                              void* d_out, int out_size, void* d_ws, size_t ws_size,
                              hipStream_t stream) {
    const int*   I = (const int*)d_in[0];
    const int*   J = (const int*)d_in[1];
    const int*   K = (const int*)d_in[2];
    const float* U = (const float*)d_in[3];   // [NUM_USER, 32]
    const float* V = (const float*)d_in[4];   // [NUM_ITEM, 32]
    const float* W = (const float*)d_in[5];   // [NUM_TIME, 32]
    const float* G = (const float*)d_in[6];   // [32, 32, 32]
    float* out = (float*)d_out;

    const int n_samples = in_sizes[0];
    const int num_time = in_sizes[5] / 32;

    const size_t h_bytes = (size_t)num_time * 1024 * sizeof(float);
    const size_t z_bytes = (size_t)(num_time + 1) * sizeof(int);   // counts + ovf_cnt
    const size_t z_pad = (z_bytes + 15) & ~(size_t)15;
    const size_t bins_bytes = (size_t)num_time * BIN_CAP * sizeof(int4);
    const size_t ovf_bytes = (size_t)n_samples * sizeof(int4);
    const size_t need_full = h_bytes + z_pad + bins_bytes + ovf_bytes;

    if (ws_size >= need_full) {
        float* H       = (float*)d_ws;
        int*   counts  = (int*)((char*)d_ws + h_bytes);      // num_time
        int*   ovf_cnt = counts + num_time;                  // 1
        int4*  bins    = (int4*)((char*)d_ws + h_bytes + z_pad);
        int4*  ovf     = (int4*)((char*)d_ws + h_bytes + z_pad + bins_bytes);

        hipMemsetAsync(counts, 0, z_bytes, stream);
        scatter_k<<<512, 256, 0, stream>>>(K, I, J, counts, bins, ovf_cnt, ovf,
                                           n_samples);
        build_H<<<(num_time + 7) / 8, 256, 0, stream>>>(G, W, H, num_time);
        tucker_eval_grouped<<<(num_time + 3) / 4, 256, 0, stream>>>(
            U, V, H, counts, bins, out, num_time);
        tucker_eval_overflow<<<64, 256, 0, stream>>>(U, V, H, ovf_cnt, ovf, out);
    } else if (ws_size >= h_bytes) {
        float* H = (float*)d_ws;
        build_H<<<(num_time + 7) / 8, 256, 0, stream>>>(G, W, H, num_time);
        const long long total_threads = (long long)n_samples * 64;
        tucker_eval<<<(int)((total_threads + 255) / 256), 256, 0, stream>>>(
            I, J, K, U, V, H, out, n_samples);
    } else {
        tucker_direct<<<(n_samples + 255) / 256, 256, 0, stream>>>(
            I, J, K, U, V, W, G, out, n_samples);
    }
}